// Round 3
// baseline (219.108 us; speedup 1.0000x reference)
//
#include <hip/hip_runtime.h>
#include <math.h>

// Problem constants (HeadAttention_738734374917)
#define Bn  8
#define Nn  2048
#define Dn  1024
#define DHn 64

typedef __attribute__((ext_vector_type(8))) short bf16x8;  // 8 bf16 = 4 VGPRs
typedef __attribute__((ext_vector_type(4))) float f32x4;

static __device__ inline short f2bf(float f) {
    unsigned u = __builtin_bit_cast(unsigned, f);
    u += 0x7FFFu + ((u >> 16) & 1u);     // round-to-nearest-even
    return (short)(u >> 16);
}
static __device__ inline float bf2f(short s) {
    unsigned u = ((unsigned)(unsigned short)s) << 16;
    return __builtin_bit_cast(float, u);
}
static __device__ inline bf16x8 pack8(float4 a, float4 b) {
    bf16x8 v;
    v[0] = f2bf(a.x); v[1] = f2bf(a.y); v[2] = f2bf(a.z); v[3] = f2bf(a.w);
    v[4] = f2bf(b.x); v[5] = f2bf(b.y); v[6] = f2bf(b.z); v[7] = f2bf(b.w);
    return v;
}

// ---------------------------------------------------------------------------
// W transpose: Wt[col 0..191][k 0..1023] bf16, col = {Q|K|V} x 64.
// ---------------------------------------------------------------------------
__global__ __launch_bounds__(256) void wt_kernel(
    const float* __restrict__ Wq, const float* __restrict__ Wk,
    const float* __restrict__ Wv, short* __restrict__ Wt)
{
    const int gn = blockIdx.x;              // 0..191
    const float* Wm = (gn < 64) ? Wq : (gn < 128 ? Wk : Wv);
    const int n = gn & 63;
    const int t = threadIdx.x;
#pragma unroll
    for (int r = 0; r < 4; ++r) {
        const int k = t * 4 + r;
        Wt[gn * Dn + k] = f2bf(Wm[k * DHn + n]);
    }
}

// ---------------------------------------------------------------------------
// Zero out (1M floats) + l (16K floats) — harness re-poisons to 0xAA.
// ---------------------------------------------------------------------------
__global__ __launch_bounds__(256) void zero_kernel(float* __restrict__ out,
                                                   float* __restrict__ l)
{
    const int id = blockIdx.x * 256 + threadIdx.x;
    const float4 z = make_float4(0.f, 0.f, 0.f, 0.f);
    if (id < 262144) ((float4*)out)[id] = z;
    else             ((float4*)l)[id - 262144] = z;
}

// ---------------------------------------------------------------------------
// K1: QKV projection via bf16 MFMA.  M-tile 32 (grid 512 -> 2 blocks/CU),
// N=192 (4 waves x 48), BK=64, register-prefetched x staging.
// Outputs: Qb[i][d], Kb[j][d] (*0.125), Vt[b][d][j] — all bf16.
// ---------------------------------------------------------------------------
__global__ __launch_bounds__(256) void qkv_kernel(
    const float* __restrict__ x, const short* __restrict__ Wt,
    const float* __restrict__ bq, const float* __restrict__ bk,
    const float* __restrict__ bv,
    short* __restrict__ Qb, short* __restrict__ Kb, short* __restrict__ Vt)
{
    __shared__ __attribute__((aligned(16))) short xs[32][72];

    const int t = threadIdx.x;
    const int w = t >> 6, lane = t & 63;
    const int c = lane & 15, quad = lane >> 4;
    const int rowbase = blockIdx.x * 32;
    const int r0 = t >> 3, kc = t & 7;      // staging: row r0 (0..31), 16B chunk kc

    float4 pf[2];
    {
        const float* p0 = &x[(size_t)(rowbase + r0) * Dn + kc * 8];
        pf[0] = *(const float4*)p0; pf[1] = *(const float4*)(p0 + 4);
    }

    f32x4 acc[2][3];
#pragma unroll
    for (int mt = 0; mt < 2; ++mt)
#pragma unroll
        for (int nt = 0; nt < 3; ++nt) acc[mt][nt] = (f32x4){0.f, 0.f, 0.f, 0.f};

    for (int kt = 0; kt < 16; ++kt) {
        __syncthreads();
        *(bf16x8*)&xs[r0][kc * 8] = pack8(pf[0], pf[1]);
        __syncthreads();
        if (kt < 15) {
            const float* p0 = &x[(size_t)(rowbase + r0) * Dn + (kt + 1) * 64 + kc * 8];
            pf[0] = *(const float4*)p0; pf[1] = *(const float4*)(p0 + 4);
        }
        const int k0 = kt * 64;
#pragma unroll
        for (int kk = 0; kk < 2; ++kk) {
            bf16x8 bfr[3];
#pragma unroll
            for (int nt = 0; nt < 3; ++nt)
                bfr[nt] = *(const bf16x8*)&Wt[(size_t)(w * 48 + nt * 16 + c) * Dn
                                              + k0 + kk * 32 + quad * 8];
#pragma unroll
            for (int mt = 0; mt < 2; ++mt) {
                const bf16x8 af = *(const bf16x8*)&xs[mt * 16 + c][kk * 32 + quad * 8];
#pragma unroll
                for (int nt = 0; nt < 3; ++nt)
                    acc[mt][nt] = __builtin_amdgcn_mfma_f32_16x16x32_bf16(
                        af, bfr[nt], acc[mt][nt], 0, 0, 0);
            }
        }
    }

#pragma unroll
    for (int nt = 0; nt < 3; ++nt) {
        const int col = w * 48 + nt * 16 + c;
        const int mat = col >> 6, cm = col & 63;   // mat uniform per (w,nt)
        const float bias = (mat == 0 ? bq : (mat == 1 ? bk : bv))[cm];
#pragma unroll
        for (int mt = 0; mt < 2; ++mt) {
#pragma unroll
            for (int r = 0; r < 4; ++r) {
                const int row = rowbase + mt * 16 + quad * 4 + r;
                const float o = acc[mt][nt][r] + bias;
                if (mat == 0)      Qb[(size_t)row * DHn + cm] = f2bf(o);
                else if (mat == 1) Kb[(size_t)row * DHn + cm] = f2bf(o * 0.125f);
                else {
                    const int b = row >> 11, i = row & (Nn - 1);
                    Vt[((size_t)b * DHn + cm) * Nn + i] = f2bf(o);
                }
            }
        }
    }
}

// ---------------------------------------------------------------------------
// K2: l[j] = sum_i exp(Q_i . K'_j).  Block = (b, j-tile 64, i-split of 4).
// NO LDS staging: A/B fragments are direct 16B global loads (row-major bf16
// matches the mfma frag layout).  Barrier-free i-loop, atomicAdd into l.
// ---------------------------------------------------------------------------
__global__ __launch_bounds__(256) void colsum_kernel(
    const short* __restrict__ Qb, const short* __restrict__ Kb,
    float* __restrict__ l)
{
    __shared__ float red[16][64];

    const int t = threadIdx.x;
    const int w = t >> 6, lane = t & 63;
    const int c = lane & 15, quad = lane >> 4;
    const int bid = blockIdx.x;
    const int b = bid >> 7, rem = bid & 127, jt = rem >> 2, s = rem & 3;
    const int jbase = jt * 64;

    // K' B-frags: resident in registers for the whole kernel
    bf16x8 kb[4][2];
#pragma unroll
    for (int nt = 0; nt < 4; ++nt)
#pragma unroll
        for (int kk = 0; kk < 2; ++kk)
            kb[nt][kk] = *(const bf16x8*)&Kb[((size_t)b * Nn + jbase + nt * 16 + c) * DHn
                                             + kk * 32 + quad * 8];

    float lsum[4] = {0.f, 0.f, 0.f, 0.f};

#pragma unroll
    for (int ch = 0; ch < 8; ++ch) {
        const int i0 = s * 512 + (ch * 4 + w) * 16;
        const bf16x8 aq0 = *(const bf16x8*)&Qb[((size_t)b * Nn + i0 + c) * DHn + quad * 8];
        const bf16x8 aq1 = *(const bf16x8*)&Qb[((size_t)b * Nn + i0 + c) * DHn + 32 + quad * 8];
#pragma unroll
        for (int nt = 0; nt < 4; ++nt) {
            f32x4 sv = (f32x4){0.f, 0.f, 0.f, 0.f};
            sv = __builtin_amdgcn_mfma_f32_16x16x32_bf16(aq0, kb[nt][0], sv, 0, 0, 0);
            sv = __builtin_amdgcn_mfma_f32_16x16x32_bf16(aq1, kb[nt][1], sv, 0, 0, 0);
            lsum[nt] += __expf(sv[0]) + __expf(sv[1]) + __expf(sv[2]) + __expf(sv[3]);
        }
    }

#pragma unroll
    for (int nt = 0; nt < 4; ++nt) red[w * 4 + quad][nt * 16 + c] = lsum[nt];
    __syncthreads();
    if (t < 64) {
        float sum = 0.f;
#pragma unroll
        for (int r = 0; r < 16; ++r) sum += red[r][t];
        atomicAdd(&l[(size_t)b * Nn + jbase + t], sum);
    }
}

// ---------------------------------------------------------------------------
// vscale: fold 1/l_j into Vt in place:  Vt[b][d][j] *= 1/l[b][j].
// ---------------------------------------------------------------------------
__global__ __launch_bounds__(256) void vscale_kernel(
    short* __restrict__ Vt, const float* __restrict__ l)
{
    const int row = blockIdx.x;              // b*64 + d, 0..511
    const int b = row >> 6;
    const int t = threadIdx.x;
    const int j0 = t * 8;
    bf16x8 v = *(const bf16x8*)&Vt[(size_t)row * Nn + j0];
    const float4 l0 = *(const float4*)&l[(size_t)b * Nn + j0];
    const float4 l1 = *(const float4*)&l[(size_t)b * Nn + j0 + 4];
    const float rl[8] = {1.f / l0.x, 1.f / l0.y, 1.f / l0.z, 1.f / l0.w,
                         1.f / l1.x, 1.f / l1.y, 1.f / l1.z, 1.f / l1.w};
    bf16x8 o;
#pragma unroll
    for (int e = 0; e < 8; ++e) o[e] = f2bf(bf2f(v[e]) * rl[e]);
    *(bf16x8*)&Vt[(size_t)row * Nn + j0] = o;
}

// ---------------------------------------------------------------------------
// K3: out[i,:] += sum_j exp(Q_i.K'_j) * V'[j,:]   (V' pre-scaled by 1/l).
// Block = (b, i-tile 64, j-split of 4).  Q A-frags loaded ONCE; K/V' B-frags
// direct from global; only wave-private Ps LDS round-trip (no block barriers).
// ---------------------------------------------------------------------------
__global__ __launch_bounds__(256) void attnout_kernel(
    const short* __restrict__ Qb, const short* __restrict__ Kb,
    const short* __restrict__ Vt, float* __restrict__ out)
{
    __shared__ __attribute__((aligned(16))) short Ps[4][16][72]; // wave-private

    const int t = threadIdx.x;
    const int w = t >> 6, lane = t & 63;
    const int c = lane & 15, quad = lane >> 4;
    const int bid = blockIdx.x;
    const int b = bid >> 7, rem = bid & 127, it = rem >> 2, s = rem & 3;
    const int ibase = it * 64;

    // Q A-frags for this wave's 16 i-rows: constant across the j-loop
    const bf16x8 aq0 = *(const bf16x8*)&Qb[((size_t)b * Nn + ibase + w * 16 + c) * DHn + quad * 8];
    const bf16x8 aq1 = *(const bf16x8*)&Qb[((size_t)b * Nn + ibase + w * 16 + c) * DHn + 32 + quad * 8];

    f32x4 acc[4];
#pragma unroll
    for (int dn = 0; dn < 4; ++dn) acc[dn] = (f32x4){0.f, 0.f, 0.f, 0.f};

#pragma unroll 2
    for (int ch = 0; ch < 8; ++ch) {
        const int jb = s * 512 + ch * 64;
        // S = Q.K'^T (16 i x 64 j), exp -> Ps (bf16, A-layout via LDS)
#pragma unroll
        for (int nt = 0; nt < 4; ++nt) {
            const bf16x8 kb0 = *(const bf16x8*)&Kb[((size_t)b * Nn + jb + nt * 16 + c) * DHn + quad * 8];
            const bf16x8 kb1 = *(const bf16x8*)&Kb[((size_t)b * Nn + jb + nt * 16 + c) * DHn + 32 + quad * 8];
            f32x4 sv = (f32x4){0.f, 0.f, 0.f, 0.f};
            sv = __builtin_amdgcn_mfma_f32_16x16x32_bf16(aq0, kb0, sv, 0, 0, 0);
            sv = __builtin_amdgcn_mfma_f32_16x16x32_bf16(aq1, kb1, sv, 0, 0, 0);
#pragma unroll
            for (int r = 0; r < 4; ++r)
                Ps[w][quad * 4 + r][nt * 16 + c] = f2bf(__expf(sv[r]));
        }
        // wave-private LDS: same-wave DS ops are in-order; no block barrier
        const bf16x8 ap0 = *(const bf16x8*)&Ps[w][c][quad * 8];
        const bf16x8 ap1 = *(const bf16x8*)&Ps[w][c][32 + quad * 8];
#pragma unroll
        for (int dn = 0; dn < 4; ++dn) {
            const bf16x8 vb0 = *(const bf16x8*)&Vt[((size_t)b * DHn + dn * 16 + c) * Nn + jb + quad * 8];
            const bf16x8 vb1 = *(const bf16x8*)&Vt[((size_t)b * DHn + dn * 16 + c) * Nn + jb + 32 + quad * 8];
            acc[dn] = __builtin_amdgcn_mfma_f32_16x16x32_bf16(ap0, vb0, acc[dn], 0, 0, 0);
            acc[dn] = __builtin_amdgcn_mfma_f32_16x16x32_bf16(ap1, vb1, acc[dn], 0, 0, 0);
        }
    }

#pragma unroll
    for (int dn = 0; dn < 4; ++dn)
#pragma unroll
        for (int r = 0; r < 4; ++r)
            atomicAdd(&out[((size_t)b * Nn + ibase + w * 16 + quad * 4 + r) * DHn
                           + dn * 16 + c], acc[dn][r]);
}

// ---------------------------------------------------------------------------
extern "C" void kernel_launch(void* const* d_in, const int* in_sizes, int n_in,
                              void* d_out, int out_size, void* d_ws, size_t ws_size,
                              hipStream_t stream)
{
    const float* x  = (const float*)d_in[0];
    const float* Wq = (const float*)d_in[1];
    const float* bq = (const float*)d_in[2];
    const float* Wk = (const float*)d_in[3];
    const float* bk = (const float*)d_in[4];
    const float* Wv = (const float*)d_in[5];
    const float* bv = (const float*)d_in[6];
    float* out = (float*)d_out;

    char* ws = (char*)d_ws;
    short* Qb = (short*)(ws);                            // 2 MB
    short* Kb = (short*)(ws + (size_t)(1 << 21));        // 2 MB
    short* Vt = (short*)(ws + (size_t)(2 << 21));        // 2 MB (transposed [b][d][j])
    short* Wt = (short*)(ws + (size_t)(3 << 21));        // 384 KB
    float* lv = (float*)(ws + (size_t)(3 << 21) + (1 << 19));  // 64 KB

    zero_kernel<<<dim3(1040), dim3(256), 0, stream>>>(out, lv);
    wt_kernel<<<dim3(192), dim3(256), 0, stream>>>(Wq, Wk, Wv, Wt);
    qkv_kernel<<<dim3(512), dim3(256), 0, stream>>>(x, Wt, bq, bk, bv, Qb, Kb, Vt);
    colsum_kernel<<<dim3(1024), dim3(256), 0, stream>>>(Qb, Kb, lv);
    vscale_kernel<<<dim3(512), dim3(256), 0, stream>>>(Vt, lv);
    attnout_kernel<<<dim3(1024), dim3(256), 0, stream>>>(Qb, Kb, Vt, out);
}

// Round 4
// 161.778 us; speedup vs baseline: 1.3544x; 1.3544x over previous
//
#include <hip/hip_runtime.h>
#include <math.h>

// Problem constants (HeadAttention_738734374917)
#define Bn  8
#define Nn  2048
#define Dn  1024
#define DHn 64
#define PAD 88   // LDS row pitch (shorts): 176 B = 16B-aligned rows, 2-way banks on frag reads (free)

typedef __attribute__((ext_vector_type(8))) short bf16x8;  // 8 bf16 = 4 VGPRs
typedef __attribute__((ext_vector_type(4))) float f32x4;

static __device__ inline short f2bf(float f) {
    unsigned u = __builtin_bit_cast(unsigned, f);
    u += 0x7FFFu + ((u >> 16) & 1u);     // round-to-nearest-even
    return (short)(u >> 16);
}
static __device__ inline float bf2f(short s) {
    unsigned u = ((unsigned)(unsigned short)s) << 16;
    return __builtin_bit_cast(float, u);
}
static __device__ inline bf16x8 pack8(float4 a, float4 b) {
    bf16x8 v;
    v[0] = f2bf(a.x); v[1] = f2bf(a.y); v[2] = f2bf(a.z); v[3] = f2bf(a.w);
    v[4] = f2bf(b.x); v[5] = f2bf(b.y); v[6] = f2bf(b.z); v[7] = f2bf(b.w);
    return v;
}

// ---------------------------------------------------------------------------
// W transpose: Wt[col 0..191][k 0..1023] bf16, col = {Q|K|V} x 64.
// ---------------------------------------------------------------------------
__global__ __launch_bounds__(256) void wt_kernel(
    const float* __restrict__ Wq, const float* __restrict__ Wk,
    const float* __restrict__ Wv, short* __restrict__ Wt)
{
    const int gn = blockIdx.x;              // 0..191
    const float* Wm = (gn < 64) ? Wq : (gn < 128 ? Wk : Wv);
    const int n = gn & 63;
    const int t = threadIdx.x;
#pragma unroll
    for (int r = 0; r < 4; ++r) {
        const int k = t * 4 + r;
        Wt[gn * Dn + k] = f2bf(Wm[k * DHn + n]);
    }
}

// ---------------------------------------------------------------------------
// Zero l (16K floats) — colsum atomicAdds into it.
// ---------------------------------------------------------------------------
__global__ __launch_bounds__(256) void zero_l_kernel(float* __restrict__ l)
{
    const int id = blockIdx.x * 256 + threadIdx.x;   // 4096 float4
    ((float4*)l)[id] = make_float4(0.f, 0.f, 0.f, 0.f);
}

// ---------------------------------------------------------------------------
// K1: QKV projection, bf16 MFMA.  Grid (256 i-tiles, 3 mats) = 768 blocks
// (3/CU).  Block: 64 i x 64 n, BK=64, register prefetch of x (fp32->bf16)
// and Wt.  mat: 0->Qb[i][d], 1->Kb[j][d]*0.125, 2->Vt[b][d][j].
// ---------------------------------------------------------------------------
__global__ __launch_bounds__(256) void qkv_kernel(
    const float* __restrict__ x, const short* __restrict__ Wt,
    const float* __restrict__ bq, const float* __restrict__ bk,
    const float* __restrict__ bv,
    short* __restrict__ Qb, short* __restrict__ Kb, short* __restrict__ Vt)
{
    __shared__ __attribute__((aligned(16))) short xs[64][PAD];
    __shared__ __attribute__((aligned(16))) short wst[64][PAD];

    const int t = threadIdx.x;
    const int w = t >> 6, lane = t & 63;
    const int c = lane & 15, quad = lane >> 4;
    const int ibase = blockIdx.x * 64;
    const int mat = blockIdx.y;            // 0=Q 1=K 2=V (uniform per block)
    const int r0 = t >> 2, cc = (t & 3) * 16;   // staging: row r0, 16-elem chunk

    // prefetch kt=0
    float4 px0, px1, px2, px3; bf16x8 pw0, pw1;
    {
        const float* px = &x[(size_t)(ibase + r0) * Dn + cc];
        px0 = ((const float4*)px)[0]; px1 = ((const float4*)px)[1];
        px2 = ((const float4*)px)[2]; px3 = ((const float4*)px)[3];
        const short* pw = &Wt[(size_t)(mat * 64 + r0) * Dn + cc];
        pw0 = *(const bf16x8*)pw; pw1 = *(const bf16x8*)(pw + 8);
    }

    f32x4 acc[4];
#pragma unroll
    for (int nt = 0; nt < 4; ++nt) acc[nt] = (f32x4){0.f, 0.f, 0.f, 0.f};

    for (int kt = 0; kt < 16; ++kt) {
        __syncthreads();
        *(bf16x8*)&xs[r0][cc]      = pack8(px0, px1);
        *(bf16x8*)&xs[r0][cc + 8]  = pack8(px2, px3);
        *(bf16x8*)&wst[r0][cc]     = pw0;
        *(bf16x8*)&wst[r0][cc + 8] = pw1;
        __syncthreads();
        if (kt < 15) {
            const int k0 = (kt + 1) * 64;
            const float* px = &x[(size_t)(ibase + r0) * Dn + k0 + cc];
            px0 = ((const float4*)px)[0]; px1 = ((const float4*)px)[1];
            px2 = ((const float4*)px)[2]; px3 = ((const float4*)px)[2 + 1];
            const short* pw = &Wt[(size_t)(mat * 64 + r0) * Dn + k0 + cc];
            pw0 = *(const bf16x8*)pw; pw1 = *(const bf16x8*)(pw + 8);
        }
#pragma unroll
        for (int kk = 0; kk < 2; ++kk) {
            const bf16x8 af = *(const bf16x8*)&xs[w * 16 + c][kk * 32 + quad * 8];
#pragma unroll
            for (int nt = 0; nt < 4; ++nt) {
                const bf16x8 bf = *(const bf16x8*)&wst[nt * 16 + c][kk * 32 + quad * 8];
                acc[nt] = __builtin_amdgcn_mfma_f32_16x16x32_bf16(af, bf, acc[nt], 0, 0, 0);
            }
        }
    }

    // epilogue (mat uniform per block)
    const float* bias = (mat == 0) ? bq : ((mat == 1) ? bk : bv);
    const int b = ibase >> 11, ib = ibase & (Nn - 1);
#pragma unroll
    for (int nt = 0; nt < 4; ++nt) {
        const int d = nt * 16 + c;
        const float bi = bias[d];
        if (mat == 2) {
            ushort4 o;
            o.x = (unsigned short)f2bf(acc[nt][0] + bi);
            o.y = (unsigned short)f2bf(acc[nt][1] + bi);
            o.z = (unsigned short)f2bf(acc[nt][2] + bi);
            o.w = (unsigned short)f2bf(acc[nt][3] + bi);
            *(ushort4*)&Vt[((size_t)b * DHn + d) * Nn + ib + w * 16 + quad * 4] = o;
        } else {
            const float s = (mat == 1) ? 0.125f : 1.0f;
            short* Out = (mat == 0) ? Qb : Kb;
#pragma unroll
            for (int r = 0; r < 4; ++r)
                Out[(size_t)(ibase + w * 16 + quad * 4 + r) * DHn + d] =
                    f2bf((acc[nt][r] + bi) * s);
        }
    }
}

// ---------------------------------------------------------------------------
// K2: l[j] = sum_i exp(Q_i . K'_j).  Grid = (b, j-tile 64, i-split 4) = 1024.
// K-frags register-resident (one-time scattered load); Q staged coalesced
// into LDS per 64-row tile.  LDS reduce -> atomicAdd into zeroed l.
// ---------------------------------------------------------------------------
__global__ __launch_bounds__(256) void colsum_kernel(
    const short* __restrict__ Qb, const short* __restrict__ Kb,
    float* __restrict__ l)
{
    __shared__ __attribute__((aligned(16))) short Qs[64][PAD];
    __shared__ float red[16][64];

    const int t = threadIdx.x;
    const int w = t >> 6, lane = t & 63;
    const int c = lane & 15, quad = lane >> 4;
    const int bid = blockIdx.x;
    const int b = bid >> 7, rem = bid & 127, jt = rem >> 2, s = rem & 3;
    const int jbase = jt * 64;
    const int r0 = t >> 2, cc = (t & 3) * 16;

    bf16x8 kb[4][2];
#pragma unroll
    for (int nt = 0; nt < 4; ++nt)
#pragma unroll
        for (int kk = 0; kk < 2; ++kk)
            kb[nt][kk] = *(const bf16x8*)&Kb[((size_t)b * Nn + jbase + nt * 16 + c) * DHn
                                             + kk * 32 + quad * 8];

    float lsum[4] = {0.f, 0.f, 0.f, 0.f};

    for (int it = 0; it < 8; ++it) {
        const int i0 = s * 512 + it * 64;
        __syncthreads();
        const short* pq = &Qb[((size_t)b * Nn + i0 + r0) * DHn + cc];
        *(bf16x8*)&Qs[r0][cc]     = *(const bf16x8*)pq;
        *(bf16x8*)&Qs[r0][cc + 8] = *(const bf16x8*)(pq + 8);
        __syncthreads();

        const bf16x8 aq0 = *(const bf16x8*)&Qs[w * 16 + c][quad * 8];
        const bf16x8 aq1 = *(const bf16x8*)&Qs[w * 16 + c][32 + quad * 8];
#pragma unroll
        for (int nt = 0; nt < 4; ++nt) {
            f32x4 sv = (f32x4){0.f, 0.f, 0.f, 0.f};
            sv = __builtin_amdgcn_mfma_f32_16x16x32_bf16(aq0, kb[nt][0], sv, 0, 0, 0);
            sv = __builtin_amdgcn_mfma_f32_16x16x32_bf16(aq1, kb[nt][1], sv, 0, 0, 0);
            lsum[nt] += __expf(sv[0]) + __expf(sv[1]) + __expf(sv[2]) + __expf(sv[3]);
        }
    }

#pragma unroll
    for (int nt = 0; nt < 4; ++nt) red[w * 4 + quad][nt * 16 + c] = lsum[nt];
    __syncthreads();
    if (t < 64) {
        float sum = 0.f;
#pragma unroll
        for (int r = 0; r < 16; ++r) sum += red[r][t];
        atomicAdd(&l[(size_t)b * Nn + jbase + t], sum);
    }
}

// ---------------------------------------------------------------------------
// vscale: Vt[b][d][j] *= 1/l[b][j]  in place.
// ---------------------------------------------------------------------------
__global__ __launch_bounds__(256) void vscale_kernel(
    short* __restrict__ Vt, const float* __restrict__ l)
{
    const int row = blockIdx.x;              // b*64 + d, 0..511
    const int b = row >> 6;
    const int t = threadIdx.x;
    const int j0 = t * 8;
    bf16x8 v = *(const bf16x8*)&Vt[(size_t)row * Nn + j0];
    const float4 l0 = *(const float4*)&l[(size_t)b * Nn + j0];
    const float4 l1 = *(const float4*)&l[(size_t)b * Nn + j0 + 4];
    const float rl[8] = {1.f / l0.x, 1.f / l0.y, 1.f / l0.z, 1.f / l0.w,
                         1.f / l1.x, 1.f / l1.y, 1.f / l1.z, 1.f / l1.w};
    bf16x8 o;
#pragma unroll
    for (int e = 0; e < 8; ++e) o[e] = f2bf(bf2f(v[e]) * rl[e]);
    *(bf16x8*)&Vt[(size_t)row * Nn + j0] = o;
}

// ---------------------------------------------------------------------------
// K3: out_partial[s][i,:] = sum_{j in s} exp(Q_i.K'_j) * V'[j,:].
// Grid = (b, i-tile 64, j-split 4) = 1024 blocks.  Cooperative LDS staging
// of K/V' tiles (coalesced); Ps wave-private C->A bounce; PLAIN stores to
// per-split partial buffers (no atomics).
// ---------------------------------------------------------------------------
__global__ __launch_bounds__(256) void attnout_kernel(
    const short* __restrict__ Qb, const short* __restrict__ Kb,
    const short* __restrict__ Vt, float* __restrict__ outp)
{
    __shared__ __attribute__((aligned(16))) short Ks[64][PAD];
    __shared__ __attribute__((aligned(16))) short Vs[64][PAD];
    __shared__ __attribute__((aligned(16))) short Ps[4][16][PAD];  // wave-private

    const int t = threadIdx.x;
    const int w = t >> 6, lane = t & 63;
    const int c = lane & 15, quad = lane >> 4;
    const int bid = blockIdx.x;
    const int b = bid >> 7, rem = bid & 127, it = rem >> 2, s = rem & 3;
    const int ibase = it * 64;
    const int r0 = t >> 2, cc = (t & 3) * 16;

    const size_t qrow = (size_t)b * Nn + ibase + w * 16 + c;
    const bf16x8 aq0 = *(const bf16x8*)&Qb[qrow * DHn + quad * 8];
    const bf16x8 aq1 = *(const bf16x8*)&Qb[qrow * DHn + 32 + quad * 8];

    f32x4 acc[4];
#pragma unroll
    for (int dn = 0; dn < 4; ++dn) acc[dn] = (f32x4){0.f, 0.f, 0.f, 0.f};

    for (int jt2 = 0; jt2 < 8; ++jt2) {
        const int jb = s * 512 + jt2 * 64;
        __syncthreads();   // prev-iter Ks/Vs reads done
        const short* pk = &Kb[((size_t)b * Nn + jb + r0) * DHn + cc];
        *(bf16x8*)&Ks[r0][cc]     = *(const bf16x8*)pk;
        *(bf16x8*)&Ks[r0][cc + 8] = *(const bf16x8*)(pk + 8);
        const short* pv = &Vt[((size_t)b * DHn + r0) * Nn + jb + cc];
        *(bf16x8*)&Vs[r0][cc]     = *(const bf16x8*)pv;
        *(bf16x8*)&Vs[r0][cc + 8] = *(const bf16x8*)(pv + 8);
        __syncthreads();

        // S = Q.K'^T (16 i x 64 j per wave) -> exp -> Ps (A-layout bounce)
#pragma unroll
        for (int nt = 0; nt < 4; ++nt) {
            const bf16x8 kb0 = *(const bf16x8*)&Ks[nt * 16 + c][quad * 8];
            const bf16x8 kb1 = *(const bf16x8*)&Ks[nt * 16 + c][32 + quad * 8];
            f32x4 sv = (f32x4){0.f, 0.f, 0.f, 0.f};
            sv = __builtin_amdgcn_mfma_f32_16x16x32_bf16(aq0, kb0, sv, 0, 0, 0);
            sv = __builtin_amdgcn_mfma_f32_16x16x32_bf16(aq1, kb1, sv, 0, 0, 0);
#pragma unroll
            for (int r = 0; r < 4; ++r)
                Ps[w][quad * 4 + r][nt * 16 + c] = f2bf(__expf(sv[r]));
        }
        // wave-private: same-wave DS ops are in-order, no block barrier
        const bf16x8 ap0 = *(const bf16x8*)&Ps[w][c][quad * 8];
        const bf16x8 ap1 = *(const bf16x8*)&Ps[w][c][32 + quad * 8];
#pragma unroll
        for (int dn = 0; dn < 4; ++dn) {
            const bf16x8 vb0 = *(const bf16x8*)&Vs[dn * 16 + c][quad * 8];
            const bf16x8 vb1 = *(const bf16x8*)&Vs[dn * 16 + c][32 + quad * 8];
            acc[dn] = __builtin_amdgcn_mfma_f32_16x16x32_bf16(ap0, vb0, acc[dn], 0, 0, 0);
            acc[dn] = __builtin_amdgcn_mfma_f32_16x16x32_bf16(ap1, vb1, acc[dn], 0, 0, 0);
        }
    }

    float* op = outp + (size_t)s * (Bn * Nn * DHn) + ((size_t)b * Nn + ibase) * DHn;
#pragma unroll
    for (int dn = 0; dn < 4; ++dn)
#pragma unroll
        for (int r = 0; r < 4; ++r)
            op[(w * 16 + quad * 4 + r) * DHn + dn * 16 + c] = acc[dn][r];
}

// ---------------------------------------------------------------------------
// Reduce the 4 partial buffers into out.
// ---------------------------------------------------------------------------
__global__ __launch_bounds__(256) void outreduce_kernel(
    const float* __restrict__ outp, float* __restrict__ out)
{
    const int id = blockIdx.x * 256 + threadIdx.x;   // 262144 float4
    const float4* p = (const float4*)outp;
    const float4 a = p[id];
    const float4 b = p[id + 262144];
    const float4 c = p[id + 2 * 262144];
    const float4 d = p[id + 3 * 262144];
    float4 r;
    r.x = a.x + b.x + c.x + d.x;
    r.y = a.y + b.y + c.y + d.y;
    r.z = a.z + b.z + c.z + d.z;
    r.w = a.w + b.w + c.w + d.w;
    ((float4*)out)[id] = r;
}

// ---------------------------------------------------------------------------
extern "C" void kernel_launch(void* const* d_in, const int* in_sizes, int n_in,
                              void* d_out, int out_size, void* d_ws, size_t ws_size,
                              hipStream_t stream)
{
    const float* x  = (const float*)d_in[0];
    const float* Wq = (const float*)d_in[1];
    const float* bq = (const float*)d_in[2];
    const float* Wk = (const float*)d_in[3];
    const float* bk = (const float*)d_in[4];
    const float* Wv = (const float*)d_in[5];
    const float* bv = (const float*)d_in[6];
    float* out = (float*)d_out;

    char* ws = (char*)d_ws;
    short* Qb   = (short*)(ws);                                   // 2 MB
    short* Kb   = (short*)(ws + (size_t)(1 << 21));               // 2 MB
    short* Vt   = (short*)(ws + (size_t)(2 << 21));               // 2 MB [b][d][j]
    short* Wt   = (short*)(ws + (size_t)(3 << 21));               // 384 KB
    float* lv   = (float*)(ws + (size_t)(3 << 21) + (1 << 19));   // 64 KB
    float* outp = (float*)(ws + (size_t)(7 << 20));               // 16 MB (4 partials)

    zero_l_kernel<<<dim3(16), dim3(256), 0, stream>>>(lv);
    wt_kernel<<<dim3(192), dim3(256), 0, stream>>>(Wq, Wk, Wv, Wt);
    qkv_kernel<<<dim3(256, 3), dim3(256), 0, stream>>>(x, Wt, bq, bk, bv, Qb, Kb, Vt);
    colsum_kernel<<<dim3(1024), dim3(256), 0, stream>>>(Qb, Kb, lv);
    vscale_kernel<<<dim3(512), dim3(256), 0, stream>>>(Vt, lv);
    attnout_kernel<<<dim3(1024), dim3(256), 0, stream>>>(Qb, Kb, Vt, outp);
    outreduce_kernel<<<dim3(1024), dim3(256), 0, stream>>>(outp, out);
}